// Round 14
// baseline (36.633 us; speedup 1.0000x reference)
//
#include <hip/hip_runtime.h>
#include <hip/hip_fp16.h>

#define SCALE (1.0f/16.0f)

typedef __attribute__((ext_vector_type(8))) _Float16 f16x8;
typedef __attribute__((ext_vector_type(4))) float f32x4;
typedef __attribute__((ext_vector_type(16))) float f32x16;
typedef __attribute__((ext_vector_type(4))) unsigned int u32x4;
typedef unsigned int u32;

// keep 16 u32x4 W-fragments alive in VGPRs (forces issue-now, wait-at-pin)
#define PIN16(W) { _Pragma("unroll") \
    for (int s_ = 0; s_ < 16; ++s_) \
        asm volatile("" : "+v"((W)[s_][0]), "+v"((W)[s_][1]), "+v"((W)[s_][2]), "+v"((W)[s_][3])); }

__device__ __forceinline__ void gload16(const void* g, void* l) {
    __builtin_amdgcn_global_load_lds(
        (const __attribute__((address_space(1))) unsigned int*)g,
        (__attribute__((address_space(3))) unsigned int*)l, 16, 0, 0);
}
__device__ __forceinline__ __half2 asH2(u32 v) {
    union { u32 i; __half2 h; } u; u.i = v; return u.h;
}
__device__ __forceinline__ u32 asU32(__half2 h) {
    union { __half2 h; u32 i; } u; u.h = h; return u.i;
}
__device__ __forceinline__ int dupH2(float f) {
    __half h = __float2half_rn(f);
    __half2 d; d.x = h; d.y = h;
    union { __half2 h2; int i; } u; u.h2 = d; return u.i;
}

// ---------------- K1: prep = transpose (blocks 0..255) + permw (blocks 256..511) ----------------
__global__ void k_prep(const float* __restrict__ feat, __half* __restrict__ featT,
                       const float* __restrict__ wf, __half* __restrict__ wr) {
    __shared__ float t[64][65];
    int b = blockIdx.x;
    if (b < 256) {
        int cb = (b >> 6) << 6;
        int pb = (b & 63) << 6;
        int lx = threadIdx.x & 63, ly = threadIdx.x >> 6;
#pragma unroll
        for (int i = 0; i < 16; ++i) {
            int cl = i*4 + ly;
            t[cl][lx] = feat[(size_t)(cb + cl) * 4096 + pb + lx];
        }
        __syncthreads();
#pragma unroll
        for (int i = 0; i < 16; ++i) {
            int pl = i*4 + ly;
            featT[(size_t)(pb + pl) * 256 + cb + lx] = __float2half_rn(t[lx][pl]);
        }
    } else {
        int ch = (b - 256) * 256 + threadIdx.x;   // 65536 chunks
        int l  = ch & 63;
        int sk = (ch >> 6) & 15;
        int ot = (ch >> 10) & 7;
        int j  = ch >> 13;
        int o = ot*32 + (l & 31);
        int k = j*256 + sk*16 + (l >> 5)*8;
        const float* src = wf + (size_t)o*2048 + k;
        f32x4 a = *(const f32x4*)src;
        f32x4 bb = *(const f32x4*)(src + 4);
        f16x8 p;
#pragma unroll
        for (int u = 0; u < 4; ++u) p[u] = (_Float16)a[u];
#pragma unroll
        for (int u = 0; u < 4; ++u) p[4+u] = (_Float16)bb[u];
        *((f16x8*)wr + ch) = p;
    }
}

// ---------------- K2: fused ROIAlign + GEMM, 2 barrier domains per CU ----------------
// Grid 512: (n 0..127, hh 0..1, oh 0..1). 256 thr = 4 waves = (oq 0..1) x (kh 0..1).
// Block tile: 128 o x ~25 hw. Single 7-row patch + double-buffered Pl; 2 barriers/j.
__global__ void __launch_bounds__(256, 2) k_fused(
    const __half* __restrict__ featT,
    const float* __restrict__ boxes,
    const __half* __restrict__ wr,
    const float* __restrict__ bfuse,
    float* __restrict__ out)
{
    __shared__ char patch[28672];        // [y 7][px 8][c 256] fp16
    __shared__ char Pl[2][16384];        // [32 hw][256 c] fp16, full-row XOR swizzle
    __shared__ int4 tabs[4][2][7];       // [box&3][x/y][idx]
    __shared__ int  pbs[4][2];           // [box&3][xb, yb]

    int tid = threadIdx.x;
    int lane = tid & 63, wid = tid >> 6;     // 4 waves
    int r31 = lane & 31, l5 = lane >> 5;
    int oq = wid & 1, kh = wid >> 1;
    int bid = blockIdx.x;
    int n  = bid & 127;
    int hh = (bid >> 7) & 1;
    int oh = bid >> 8;
    int hw0 = hh * 25;
    int HWn = hh ? 24 : 25;

    int nb_base = (n & 15) * 8;
    int off = n >> 4;
    int t3 = off + (off >= 4 ? 1 : 0);
    int ci = t3 / 3, cj = t3 - ci*3;

    f32x16 acc0, acc1;
#pragma unroll
    for (int i = 0; i < 16; ++i) { acc0[i] = 0.f; acc1[i] = 0.f; }

    // ---- zero Pl pad rows (read by MFMA, never pooled) ----
    {
        int padrows = 32 - HWn;
        for (int i = tid; i < padrows*32*2; i += 256) {
            int b = i / (padrows*32);
            int rem = i - b*(padrows*32);
            int row = HWn + (rem >> 5), slot = rem & 31;
            *(u32x4*)(Pl[b] + row*512 + slot*16) = (u32x4){0,0,0,0};
        }
    }

    // ---- 3-tap table builder ----
    auto tablesW = [&](int jj, int isy, bool active) {
        if (active) {
            int nbx = nb_base + jj;
            float bx1 = boxes[nbx*4+0], by1 = boxes[nbx*4+1];
            float bx2 = boxes[nbx*4+2], by2 = boxes[nbx*4+3];
            float w3 = (bx2-bx1)*(1.f/3.f), h3 = (by2-by1)*(1.f/3.f);
            float org  = isy ? (by1 + ci*h3)*SCALE - 0.5f : (bx1 + cj*w3)*SCALE - 0.5f;
            float step = (isy ? h3 : w3) * (SCALE*(1.f/14.f));
            float sc = isy ? 0.25f : 1.f;
            float p = org + ((float)lane + 0.5f)*step;
            float pc = fminf(fmaxf(p, 0.f), 63.f);
            float fl = fminf(floorf(pc), 62.f);
            float fr = pc - fl;
            float c0 = __shfl(fl, 2*lane);
            float c1 = __shfl(fl, 2*lane+1);
            float f  = __shfl(fr, 2*lane);
            float f2 = __shfl(fr, 2*lane+1);
            float fl0 = __shfl(fl, 0);
            int base = min((int)fl0, 56);
            float d = c1 - c0;
            float a0 = sc*((1.f-f) + (1.f-d)*(1.f-f2));
            float a1 = sc*(f + (1.f-d)*f2 + d*(1.f-f2));
            float a2 = sc*(d*f2);
            if (lane < 7) {
                int4 e;
                e.x = (int)c0 - base;
                e.y = dupH2(a0); e.z = dupH2(a1); e.w = dupH2(a2);
                tabs[jj & 3][isy][lane] = e;
            }
            if (lane == 0) pbs[jj & 3][isy] = base;
        }
    };

    // ---- stage 7x8 px patch of box jj (28 x 1KB segments over 4 waves) ----
    auto stage = [&](int jj) {
        int xb = pbs[jj & 3][0], yb = pbs[jj & 3][1];
#pragma unroll
        for (int i = 0; i < 7; ++i) {
            int seg = wid + 4*i;            // 0..27
            int row = seg >> 2, q = seg & 3;
            const __half* src = featT + ((size_t)((yb + row)*64 + xb))*256 + q*512 + lane*8;
            gload16(src, patch + row*4096 + q*1024);
        }
    };

    // ---- pool box jj from patch -> Pl[jj&1] ----
    auto pool = [&](int jj) {
        int buf = jj & 1;
        int co = tid & 31;
        int e0 = tid >> 5;
        const char* pb = patch + co*16;
        for (int e = e0; e < HWn; e += 8) {
            int g = hw0 + e;
            int h = (g*37) >> 8, w = g - h*7;
            int4 tx = tabs[jj & 3][0][w], ty = tabs[jj & 3][1][h];
            int px0 = tx.x, py0 = ty.x;
            int lx2 = min(px0 + 2, 7), ly2 = min(py0 + 2, 6);
            const char* r0 = pb + (py0*8 + px0)*512;
            const char* r1 = pb + (min(py0+1,6)*8 + px0)*512;
            const char* r2 = pb + (ly2*8 + px0)*512;
            int dx2 = (lx2 - px0)*512;
            u32x4 F00 = *(const u32x4*)(r0);
            u32x4 F01 = *(const u32x4*)(r0 + 512);
            u32x4 F02 = *(const u32x4*)(r0 + dx2);
            u32x4 F10 = *(const u32x4*)(r1);
            u32x4 F11 = *(const u32x4*)(r1 + 512);
            u32x4 F12 = *(const u32x4*)(r1 + dx2);
            u32x4 F20 = *(const u32x4*)(r2);
            u32x4 F21 = *(const u32x4*)(r2 + 512);
            u32x4 F22 = *(const u32x4*)(r2 + dx2);
            __half2 xa = asH2(tx.y), xb2 = asH2(tx.z), xc = asH2(tx.w);
            __half2 ya = asH2(ty.y), yb2 = asH2(ty.z), yc = asH2(ty.w);
            u32x4 res;
#pragma unroll
            for (int s = 0; s < 4; ++s) {
                __half2 q0 = __hfma2(asH2(F02[s]), xc, __hfma2(asH2(F01[s]), xb2, __hmul2(asH2(F00[s]), xa)));
                __half2 q1 = __hfma2(asH2(F12[s]), xc, __hfma2(asH2(F11[s]), xb2, __hmul2(asH2(F10[s]), xa)));
                __half2 q2 = __hfma2(asH2(F22[s]), xc, __hfma2(asH2(F21[s]), xb2, __hmul2(asH2(F20[s]), xa)));
                res[s] = asU32(__hfma2(q2, yc, __hfma2(q1, yb2, __hmul2(q0, ya))));
            }
            *(u32x4*)(Pl[buf] + e*512 + ((co*16) ^ ((e & 31) << 4))) = res;
        }
    };

    // ---- W register double-buffer: wave covers 2 o-tiles x its K-half ----
    u32x4 WfA[16], WfB[16];
    auto prefW = [&](u32x4* dst, int j) {
#pragma unroll
        for (int t = 0; t < 2; ++t) {
            int otg = oh*4 + oq*2 + t;
            const u32x4* wb = (const u32x4*)wr + ((size_t)((j*8 + otg)*16 + kh*8))*64 + lane;
#pragma unroll
            for (int s = 0; s < 8; ++s) dst[t*8 + s] = wb[s*64];
        }
    };

    auto gemm = [&](const u32x4* Wsrc, int j) {
        const char* plb = (j & 1) ? Pl[1] : Pl[0];
        f16x8 pf[8];
#pragma unroll
        for (int s = 0; s < 8; ++s) {
            int sk = kh*8 + s;
            int byo = r31*512 + ((sk*32 + l5*16) ^ (r31 << 4));
            pf[s] = *(const f16x8*)(plb + byo);
        }
#pragma unroll
        for (int s = 0; s < 8; ++s) {
            acc0 = __builtin_amdgcn_mfma_f32_32x32x16_f16(
                __builtin_bit_cast(f16x8, Wsrc[s]), pf[s], acc0, 0, 0, 0);
            acc1 = __builtin_amdgcn_mfma_f32_32x32x16_f16(
                __builtin_bit_cast(f16x8, Wsrc[8 + s]), pf[s], acc1, 0, 0, 0);
        }
    };

    // ---- prologue: tables(0,1); stage(0)+prefW(0); pool(0) ----
    tablesW(wid >> 1, wid & 1, wid < 4);
    __syncthreads();
    stage(0);
    prefW(WfA, 0);
    PIN16(WfA);
    __syncthreads();               // drains stage(0) gloads
    pool(0);
    __syncthreads();

#pragma unroll
    for (int j = 0; j < 8; ++j) {
        // A: consume Pl[j&1] + Wf[j&1]; stage patch(j+1); prefetch W(j+1)
        gemm((j & 1) ? WfB : WfA, j);
        if (j < 7) {
            stage(j+1);
            prefW((j & 1) ? WfA : WfB, j+1);
            if (j & 1) { PIN16(WfA); } else { PIN16(WfB); }
        }
        __syncthreads();
        // B: pool(j+1) -> Pl[(j+1)&1]; tables(j+2)
        if (j < 7) pool(j+1);
        if (j < 6) tablesW(j+2, wid, wid < 2);
        __syncthreads();
    }

    // ---- split-K reduce (overlay on patch) + epilogue ----
    float* red = (float*)patch;      // [oq*2+t][32 hw][32 o-part] f32 = 16 KB
    if (kh == 1) {
#pragma unroll
        for (int t = 0; t < 2; ++t) {
            f32x16 a = t ? acc1 : acc0;
#pragma unroll
            for (int q4 = 0; q4 < 4; ++q4) {
                f32x4 v;
#pragma unroll
                for (int i = 0; i < 4; ++i) v[i] = a[q4*4 + i];
                *(f32x4*)((char*)red + (oq*2 + t)*4096 + r31*128 + q4*32 + l5*16) = v;
            }
        }
    }
    __syncthreads();
    if (kh == 0) {
        int hw = hw0 + r31;
        bool ok = r31 < HWn;
        float* ob = out + (size_t)n*12544 + hw;
#pragma unroll
        for (int t = 0; t < 2; ++t) {
            f32x16 a = t ? acc1 : acc0;
            int otb = oh*128 + (oq*2 + t)*32;
#pragma unroll
            for (int q4 = 0; q4 < 4; ++q4) {
                f32x4 r = *(const f32x4*)((const char*)red + (oq*2 + t)*4096 + r31*128 + q4*32 + l5*16);
#pragma unroll
                for (int i = 0; i < 4; ++i) {
                    int o = otb + q4*8 + l5*4 + i;
                    float v = a[q4*4 + i] + r[i] + bfuse[o];
                    if (ok) ob[(size_t)o*49] = fmaxf(v, 0.f);
                }
            }
        }
    }
}

extern "C" void kernel_launch(void* const* d_in, const int* in_sizes, int n_in,
                              void* d_out, int out_size, void* d_ws, size_t ws_size,
                              hipStream_t stream) {
    const float* feat  = (const float*)d_in[0];   // [256,64,64]
    const float* boxes = (const float*)d_in[1];   // [128,4]
    const float* wf    = (const float*)d_in[2];   // [256,2048]
    const float* bfuse = (const float*)d_in[3];   // [256]
    float* out = (float*)d_out;                   // [128,256,7,7]

    char* ws = (char*)d_ws;
    __half* wr    = (__half*)ws;                  // 1 MB (permuted W, fp16)
    __half* featT = (__half*)(ws + (1u<<20));     // 2 MB (fp16 feat, pix-major)

    k_prep<<<512, 256, 0, stream>>>(feat, featT, wf, wr);
    k_fused<<<512, 256, 0, stream>>>(featT, boxes, wr, bfuse, out);
}

// Round 15
// 30.368 us; speedup vs baseline: 1.2063x; 1.2063x over previous
//
#include <hip/hip_runtime.h>
#include <hip/hip_fp16.h>

#define SCALE (1.0f/16.0f)

typedef __attribute__((ext_vector_type(8))) _Float16 f16x8;
typedef __attribute__((ext_vector_type(4))) float f32x4;
typedef __attribute__((ext_vector_type(16))) float f32x16;
typedef __attribute__((ext_vector_type(4))) unsigned int u32x4;
typedef unsigned int u32;

#define PIN16(W) { _Pragma("unroll") \
    for (int s_ = 0; s_ < 16; ++s_) \
        asm volatile("" : "+v"((W)[s_][0]), "+v"((W)[s_][1]), "+v"((W)[s_][2]), "+v"((W)[s_][3])); }

__device__ __forceinline__ void gload16(const void* g, void* l) {
    __builtin_amdgcn_global_load_lds(
        (const __attribute__((address_space(1))) unsigned int*)g,
        (__attribute__((address_space(3))) unsigned int*)l, 16, 0, 0);
}
__device__ __forceinline__ __half2 asH2(u32 v) {
    union { u32 i; __half2 h; } u; u.i = v; return u.h;
}
__device__ __forceinline__ u32 asU32(__half2 h) {
    union { __half2 h; u32 i; } u; u.h = h; return u.i;
}
__device__ __forceinline__ int dupH2(float f) {
    __half h = __float2half_rn(f);
    __half2 d; d.x = h; d.y = h;
    union { __half2 h2; int i; } u; u.h2 = d; return u.i;
}

// ---------------- K1: prep = transpose (blocks 0..255) + permw (blocks 256..511) ----------------
__global__ void k_prep(const float* __restrict__ feat, __half* __restrict__ featT,
                       const float* __restrict__ wf, __half* __restrict__ wr) {
    __shared__ float t[64][65];
    int b = blockIdx.x;
    if (b < 256) {
        int cb = (b >> 6) << 6;
        int pb = (b & 63) << 6;
        int lx = threadIdx.x & 63, ly = threadIdx.x >> 6;
#pragma unroll
        for (int i = 0; i < 16; ++i) {
            int cl = i*4 + ly;
            t[cl][lx] = feat[(size_t)(cb + cl) * 4096 + pb + lx];
        }
        __syncthreads();
#pragma unroll
        for (int i = 0; i < 16; ++i) {
            int pl = i*4 + ly;
            featT[(size_t)(pb + pl) * 256 + cb + lx] = __float2half_rn(t[lx][pl]);
        }
    } else {
        int ch = (b - 256) * 256 + threadIdx.x;   // 65536 chunks
        int l  = ch & 63;
        int sk = (ch >> 6) & 15;
        int ot = (ch >> 10) & 7;
        int j  = ch >> 13;
        int o = ot*32 + (l & 31);
        int k = j*256 + sk*16 + (l >> 5)*8;
        const float* src = wf + (size_t)o*2048 + k;
        f32x4 a = *(const f32x4*)src;
        f32x4 bb = *(const f32x4*)(src + 4);
        f16x8 p;
#pragma unroll
        for (int u = 0; u < 4; ++u) p[u] = (_Float16)a[u];
#pragma unroll
        for (int u = 0; u < 4; ++u) p[4+u] = (_Float16)bb[u];
        *((f16x8*)wr + ch) = p;
    }
}

// ---------------- K2: fused ROIAlign + GEMM, producer/consumer wave specialization ----------------
// Grid 256: (n 0..127, hh 0..1). 512 thr = 8 waves.
// Waves 0-3 (producers): patch stage + FIR pool + tables (LDS/VALU stream).
// Waves 4-7 (consumers): W prefetch + full-K GEMM (L2/MFMA stream). No split-K.
__global__ void __launch_bounds__(512) k_fused(
    const __half* __restrict__ featT,
    const float* __restrict__ boxes,
    const __half* __restrict__ wr,
    const float* __restrict__ bfuse,
    float* __restrict__ out)
{
    __shared__ char patch[2][28672];     // [buf][y 7][px 8][c 256] fp16
    __shared__ char Pl[2][16384];        // [buf][32 hw][256 c] fp16, full-row XOR swizzle
    __shared__ int4 tabs[4][2][7];       // [box&3][x/y][idx]
    __shared__ int  pbs[4][2];           // [box&3][xb, yb]

    int tid = threadIdx.x;
    int lane = tid & 63, wid = tid >> 6;     // 8 waves
    int r31 = lane & 31, l5 = lane >> 5;
    int bid = blockIdx.x;
    int n  = bid & 127;
    int hh = bid >> 7;
    int hw0 = hh * 32;
    int HWn = hh ? 17 : 32;
    bool producer = wid < 4;

    int nb_base = (n & 15) * 8;
    int off = n >> 4;
    int t3 = off + (off >= 4 ? 1 : 0);
    int ci = t3 / 3, cj = t3 - ci*3;

    // ---- zero Pl pad rows (rows HWn..31, both buffers) ----
    {
        int padrows = 32 - HWn;
        for (int i = tid; i < padrows*32*2; i += 512) {
            int b = i / (padrows*32);
            int rem = i - b*(padrows*32);
            int row = HWn + (rem >> 5), slot = rem & 31;
            *(u32x4*)(Pl[b] + row*512 + slot*16) = (u32x4){0,0,0,0};
        }
    }

    // ---- 3-tap table builder (waves 0,1: isy = wid) ----
    auto tablesW = [&](int jj, int isy, bool active) {
        if (active) {
            int nbx = nb_base + jj;
            float bx1 = boxes[nbx*4+0], by1 = boxes[nbx*4+1];
            float bx2 = boxes[nbx*4+2], by2 = boxes[nbx*4+3];
            float w3 = (bx2-bx1)*(1.f/3.f), h3 = (by2-by1)*(1.f/3.f);
            float org  = isy ? (by1 + ci*h3)*SCALE - 0.5f : (bx1 + cj*w3)*SCALE - 0.5f;
            float step = (isy ? h3 : w3) * (SCALE*(1.f/14.f));
            float sc = isy ? 0.25f : 1.f;
            float p = org + ((float)lane + 0.5f)*step;
            float pc = fminf(fmaxf(p, 0.f), 63.f);
            float fl = fminf(floorf(pc), 62.f);
            float fr = pc - fl;
            float c0 = __shfl(fl, 2*lane);
            float c1 = __shfl(fl, 2*lane+1);
            float f  = __shfl(fr, 2*lane);
            float f2 = __shfl(fr, 2*lane+1);
            float fl0 = __shfl(fl, 0);
            int base = min((int)fl0, 56);
            float d = c1 - c0;
            float a0 = sc*((1.f-f) + (1.f-d)*(1.f-f2));
            float a1 = sc*(f + (1.f-d)*f2 + d*(1.f-f2));
            float a2 = sc*(d*f2);
            if (lane < 7) {
                int4 e;
                e.x = (int)c0 - base;
                e.y = dupH2(a0); e.z = dupH2(a1); e.w = dupH2(a2);
                tabs[jj & 3][isy][lane] = e;
            }
            if (lane == 0) pbs[jj & 3][isy] = base;
        }
    };

    // ---- stage 7x8 px patch of box jj into patch[jj&1] (producer waves, 7 segs each) ----
    auto stage = [&](int jj) {
        int xb = pbs[jj & 3][0], yb = pbs[jj & 3][1];
        char* pd = patch[jj & 1];
#pragma unroll
        for (int i = 0; i < 7; ++i) {
            int seg = wid + 4*i;            // 0..27
            int row = seg >> 2, q = seg & 3;
            const __half* src = featT + ((size_t)((yb + row)*64 + xb))*256 + q*512 + lane*8;
            gload16(src, pd + row*4096 + q*1024);
        }
    };

    // ---- pool box jj from patch[jj&1] -> Pl[jj&1] (producer waves: 256 thr) ----
    auto pool = [&](int jj) {
        int buf = jj & 1;
        int co = tid & 31;
        int e0 = tid >> 5;                   // 0..7
        const char* pb = patch[buf] + co*16;
        for (int e = e0; e < HWn; e += 8) {
            int g = hw0 + e;
            int h = (g*37) >> 8, w = g - h*7;
            int4 tx = tabs[jj & 3][0][w], ty = tabs[jj & 3][1][h];
            int px0 = tx.x, py0 = ty.x;
            int lx2 = min(px0 + 2, 7), ly2 = min(py0 + 2, 6);
            const char* r0 = pb + (py0*8 + px0)*512;
            const char* r1 = pb + (min(py0+1,6)*8 + px0)*512;
            const char* r2 = pb + (ly2*8 + px0)*512;
            int dx2 = (lx2 - px0)*512;
            u32x4 F00 = *(const u32x4*)(r0);
            u32x4 F01 = *(const u32x4*)(r0 + 512);
            u32x4 F02 = *(const u32x4*)(r0 + dx2);
            u32x4 F10 = *(const u32x4*)(r1);
            u32x4 F11 = *(const u32x4*)(r1 + 512);
            u32x4 F12 = *(const u32x4*)(r1 + dx2);
            u32x4 F20 = *(const u32x4*)(r2);
            u32x4 F21 = *(const u32x4*)(r2 + 512);
            u32x4 F22 = *(const u32x4*)(r2 + dx2);
            __half2 xa = asH2(tx.y), xb2 = asH2(tx.z), xc = asH2(tx.w);
            __half2 ya = asH2(ty.y), yb2 = asH2(ty.z), yc = asH2(ty.w);
            u32x4 res;
#pragma unroll
            for (int s = 0; s < 4; ++s) {
                __half2 q0 = __hfma2(asH2(F02[s]), xc, __hfma2(asH2(F01[s]), xb2, __hmul2(asH2(F00[s]), xa)));
                __half2 q1 = __hfma2(asH2(F12[s]), xc, __hfma2(asH2(F11[s]), xb2, __hmul2(asH2(F10[s]), xa)));
                __half2 q2 = __hfma2(asH2(F22[s]), xc, __hfma2(asH2(F21[s]), xb2, __hmul2(asH2(F20[s]), xa)));
                res[s] = asU32(__hfma2(q2, yc, __hfma2(q1, yb2, __hmul2(q0, ya))));
            }
            *(u32x4*)(Pl[buf] + e*512 + ((co*16) ^ ((e & 31) << 4))) = res;
        }
    };

    // ---- consumer state: W for 2 o-tiles x full K, single-buffered halves ----
    int cw = wid - 4;                        // 0..3
    u32x4 Wf[32];                            // [t 2][sk 16]
    f32x16 acc0, acc1;
#pragma unroll
    for (int i = 0; i < 16; ++i) { acc0[i] = 0.f; acc1[i] = 0.f; }

    auto prefW_half = [&](int j, int sb) {
#pragma unroll
        for (int t = 0; t < 2; ++t) {
            int otg = cw*2 + t;
            const u32x4* wb = (const u32x4*)wr + ((size_t)((j*8 + otg)*16))*64 + lane;
#pragma unroll
            for (int s = 0; s < 8; ++s) Wf[t*16 + sb*8 + s] = wb[(sb*8 + s)*64];
        }
    };

    auto gemm_half = [&](int j, int sb) {
        const char* plb = (j & 1) ? Pl[1] : Pl[0];
#pragma unroll
        for (int s = 0; s < 8; ++s) {
            int sk = sb*8 + s;
            int byo = r31*512 + ((sk*32 + l5*16) ^ (r31 << 4));
            f16x8 pf = *(const f16x8*)(plb + byo);
            acc0 = __builtin_amdgcn_mfma_f32_32x32x16_f16(
                __builtin_bit_cast(f16x8, Wf[sk]), pf, acc0, 0, 0, 0);
            acc1 = __builtin_amdgcn_mfma_f32_32x32x16_f16(
                __builtin_bit_cast(f16x8, Wf[16 + sk]), pf, acc1, 0, 0, 0);
        }
    };

    // ---- prologue ----
    if (wid < 2) { tablesW(0, wid, true); tablesW(1, wid, true); tablesW(2, wid, true); }
    __syncthreads();                       // pads + tabs visible
    if (producer) { stage(0); stage(1); }
    else          { prefW_half(0, 0); prefW_half(0, 1); PIN16(Wf); PIN16((Wf+16)); }
    __syncthreads();                       // stage(0,1) drained
    if (producer) pool(0);
    __syncthreads();

    // ---- main loop: 1 barrier per j ----
#pragma unroll
    for (int j = 0; j < 8; ++j) {
        if (producer) {
            if (j < 6) stage(j+2);                 // -> patch[j&1]
            if (j < 7) pool(j+1);                  // patch[(j+1)&1] -> Pl[(j+1)&1]
            if (j < 5) tablesW(j+3, wid, wid < 2);
        } else {
            gemm_half(j, 0);
            if (j < 7) prefW_half(j+1, 0);
            gemm_half(j, 1);
            if (j < 7) { prefW_half(j+1, 1); PIN16(Wf); PIN16((Wf+16)); }
        }
        __syncthreads();
    }

    // ---- epilogue: consumers write out (bias + relu) ----
    if (!producer) {
        int hw = hw0 + r31;
        bool ok = r31 < HWn;
        float* ob = out + (size_t)n*12544 + hw;
#pragma unroll
        for (int t = 0; t < 2; ++t) {
            f32x16 a = t ? acc1 : acc0;
            int otb = (cw*2 + t)*32;
#pragma unroll
            for (int reg = 0; reg < 16; ++reg) {
                int o = otb + (reg & 3) + 8*(reg >> 2) + 4*l5;
                float v = a[reg] + bfuse[o];
                if (ok) ob[(size_t)o*49] = fmaxf(v, 0.f);
            }
        }
    }
}

extern "C" void kernel_launch(void* const* d_in, const int* in_sizes, int n_in,
                              void* d_out, int out_size, void* d_ws, size_t ws_size,
                              hipStream_t stream) {
    const float* feat  = (const float*)d_in[0];   // [256,64,64]
    const float* boxes = (const float*)d_in[1];   // [128,4]
    const float* wf    = (const float*)d_in[2];   // [256,2048]
    const float* bfuse = (const float*)d_in[3];   // [256]
    float* out = (float*)d_out;                   // [128,256,7,7]

    char* ws = (char*)d_ws;
    __half* wr    = (__half*)ws;                  // 1 MB (permuted W, fp16)
    __half* featT = (__half*)(ws + (1u<<20));     // 2 MB (fp16 feat, pix-major)

    k_prep<<<512, 256, 0, stream>>>(feat, featT, wf, wr);
    k_fused<<<256, 512, 0, stream>>>(featT, boxes, wr, bfuse, out);
}

// Round 16
// 29.614 us; speedup vs baseline: 1.2370x; 1.0254x over previous
//
#include <hip/hip_runtime.h>
#include <hip/hip_fp16.h>

#define SCALE (1.0f/16.0f)

typedef __attribute__((ext_vector_type(8))) _Float16 f16x8;
typedef __attribute__((ext_vector_type(4))) float f32x4;
typedef __attribute__((ext_vector_type(16))) float f32x16;
typedef __attribute__((ext_vector_type(4))) unsigned int u32x4;
typedef unsigned int u32;

__device__ __forceinline__ void gload16(const void* g, void* l) {
    __builtin_amdgcn_global_load_lds(
        (const __attribute__((address_space(1))) unsigned int*)g,
        (__attribute__((address_space(3))) unsigned int*)l, 16, 0, 0);
}
__device__ __forceinline__ __half2 asH2(u32 v) {
    union { u32 i; __half2 h; } u; u.i = v; return u.h;
}
__device__ __forceinline__ u32 asU32(__half2 h) {
    union { __half2 h; u32 i; } u; u.h = h; return u.i;
}
__device__ __forceinline__ int dupH2(float f) {
    __half h = __float2half_rn(f);
    __half2 d; d.x = h; d.y = h;
    union { __half2 h2; int i; } u; u.h2 = d; return u.i;
}

// ---------------- K1: prep = transpose (blocks 0..255) + permw (blocks 256..511) ----------------
__global__ void k_prep(const float* __restrict__ feat, __half* __restrict__ featT,
                       const float* __restrict__ wf, __half* __restrict__ wr) {
    __shared__ float t[64][65];
    int b = blockIdx.x;
    if (b < 256) {
        int cb = (b >> 6) << 6;
        int pb = (b & 63) << 6;
        int lx = threadIdx.x & 63, ly = threadIdx.x >> 6;
#pragma unroll
        for (int i = 0; i < 16; ++i) {
            int cl = i*4 + ly;
            t[cl][lx] = feat[(size_t)(cb + cl) * 4096 + pb + lx];
        }
        __syncthreads();
#pragma unroll
        for (int i = 0; i < 16; ++i) {
            int pl = i*4 + ly;
            featT[(size_t)(pb + pl) * 256 + cb + lx] = __float2half_rn(t[lx][pl]);
        }
    } else {
        int ch = (b - 256) * 256 + threadIdx.x;
        int l  = ch & 63;
        int sk = (ch >> 6) & 15;
        int ot = (ch >> 10) & 7;
        int j  = ch >> 13;
        int o = ot*32 + (l & 31);
        int k = j*256 + sk*16 + (l >> 5)*8;
        const float* src = wf + (size_t)o*2048 + k;
        f32x4 a = *(const f32x4*)src;
        f32x4 bb = *(const f32x4*)(src + 4);
        f16x8 p;
#pragma unroll
        for (int u = 0; u < 4; ++u) p[u] = (_Float16)a[u];
#pragma unroll
        for (int u = 0; u < 4; ++u) p[4+u] = (_Float16)bb[u];
        *((f16x8*)wr + ch) = p;
    }
}

// ---------------- K2: fused ROIAlign + GEMM, prod/cons + raw barriers + counted vmcnt ----------------
__global__ void __launch_bounds__(512) k_fused(
    const __half* __restrict__ featT,
    const float* __restrict__ boxes,
    const __half* __restrict__ wr,
    const float* __restrict__ bfuse,
    float* __restrict__ out)
{
    __shared__ char patch[3][28672];
    __shared__ char Pl[2][16384];
    __shared__ int4 tabs[4][2][7];
    __shared__ int  pbs[4][2];
    __shared__ float bx_lds[32];

    int tid = threadIdx.x;
    int lane = tid & 63, wid = tid >> 6;
    int r31 = lane & 31, l5 = lane >> 5;
    int bid = blockIdx.x;
    int n  = bid & 127;
    int hh = bid >> 7;
    int hw0 = hh * 32;
    int HWn = hh ? 17 : 32;
    bool producer = wid < 4;

    int nb_base = (n & 15) * 8;
    int off = n >> 4;
    int t3 = off + (off >= 4 ? 1 : 0);
    int ci = t3 / 3, cj = t3 - ci*3;

    if (tid < 32) bx_lds[tid] = boxes[nb_base*4 + tid];
    {
        int padrows = 32 - HWn;
        for (int i = tid; i < padrows*32*2; i += 512) {
            int b = i / (padrows*32);
            int rem = i - b*(padrows*32);
            int row = HWn + (rem >> 5), slot = rem & 31;
            *(u32x4*)(Pl[b] + row*512 + slot*16) = (u32x4){0,0,0,0};
        }
    }

    auto tablesW = [&](int jj) {
        if (wid < 2) {
            int isy = wid;
            float bx1 = bx_lds[jj*4+0], by1 = bx_lds[jj*4+1];
            float bx2 = bx_lds[jj*4+2], by2 = bx_lds[jj*4+3];
            float w3 = (bx2-bx1)*(1.f/3.f), h3 = (by2-by1)*(1.f/3.f);
            float org  = isy ? (by1 + ci*h3)*SCALE - 0.5f : (bx1 + cj*w3)*SCALE - 0.5f;
            float step = (isy ? h3 : w3) * (SCALE*(1.f/14.f));
            float sc = isy ? 0.25f : 1.f;
            float p = org + ((float)lane + 0.5f)*step;
            float pc = fminf(fmaxf(p, 0.f), 63.f);
            float fl = fminf(floorf(pc), 62.f);
            float fr = pc - fl;
            float c0 = __shfl(fl, 2*lane);
            float c1 = __shfl(fl, 2*lane+1);
            float f  = __shfl(fr, 2*lane);
            float f2 = __shfl(fr, 2*lane+1);
            float fl0 = __shfl(fl, 0);
            int base = min((int)fl0, 56);
            float d = c1 - c0;
            float a0 = sc*((1.f-f) + (1.f-d)*(1.f-f2));
            float a1 = sc*(f + (1.f-d)*f2 + d*(1.f-f2));
            float a2 = sc*(d*f2);
            if (lane < 7) {
                int4 e;
                e.x = (int)c0 - base;
                e.y = dupH2(a0); e.z = dupH2(a1); e.w = dupH2(a2);
                tabs[jj & 3][isy][lane] = e;
            }
            if (lane == 0) pbs[jj & 3][isy] = base;
        }
    };

    auto stage = [&](int jj) {           // exactly 7 gload16 per producer wave
        int xb = pbs[jj & 3][0], yb = pbs[jj & 3][1];
        char* pd = patch[jj % 3];
#pragma unroll
        for (int i = 0; i < 7; ++i) {
            int seg = wid + 4*i;
            int row = seg >> 2, q = seg & 3;
            const __half* src = featT + ((size_t)((yb + row)*64 + xb))*256 + q*512 + lane*8;
            gload16(src, pd + row*4096 + q*1024);
        }
    };

    auto pool = [&](int jj) {            // LDS-only
        int buf = jj & 1;
        int co = tid & 31;
        int e0 = tid >> 5;
        const char* pb = patch[jj % 3] + co*16;
        for (int e = e0; e < HWn; e += 8) {
            int g = hw0 + e;
            int h = (g*37) >> 8, w = g - h*7;
            int4 tx = tabs[jj & 3][0][w], ty = tabs[jj & 3][1][h];
            int px0 = tx.x, py0 = ty.x;
            int lx2 = min(px0 + 2, 7), ly2 = min(py0 + 2, 6);
            const char* r0 = pb + (py0*8 + px0)*512;
            const char* r1 = pb + (min(py0+1,6)*8 + px0)*512;
            const char* r2 = pb + (ly2*8 + px0)*512;
            int dx2 = (lx2 - px0)*512;
            u32x4 F00 = *(const u32x4*)(r0);
            u32x4 F01 = *(const u32x4*)(r0 + 512);
            u32x4 F02 = *(const u32x4*)(r0 + dx2);
            u32x4 F10 = *(const u32x4*)(r1);
            u32x4 F11 = *(const u32x4*)(r1 + 512);
            u32x4 F12 = *(const u32x4*)(r1 + dx2);
            u32x4 F20 = *(const u32x4*)(r2);
            u32x4 F21 = *(const u32x4*)(r2 + 512);
            u32x4 F22 = *(const u32x4*)(r2 + dx2);
            __half2 xa = asH2(tx.y), xb2 = asH2(tx.z), xc = asH2(tx.w);
            __half2 ya = asH2(ty.y), yb2 = asH2(ty.z), yc = asH2(ty.w);
            u32x4 res;
#pragma unroll
            for (int s = 0; s < 4; ++s) {
                __half2 q0 = __hfma2(asH2(F02[s]), xc, __hfma2(asH2(F01[s]), xb2, __hmul2(asH2(F00[s]), xa)));
                __half2 q1 = __hfma2(asH2(F12[s]), xc, __hfma2(asH2(F11[s]), xb2, __hmul2(asH2(F10[s]), xa)));
                __half2 q2 = __hfma2(asH2(F22[s]), xc, __hfma2(asH2(F21[s]), xb2, __hmul2(asH2(F20[s]), xa)));
                res[s] = asU32(__hfma2(q2, yc, __hfma2(q1, yb2, __hmul2(q0, ya))));
            }
            *(u32x4*)(Pl[buf] + e*512 + ((co*16) ^ ((e & 31) << 4))) = res;
        }
    };

    // consumer: 2 o-tiles x 16 sk, half-interleaved reload (R15 layout)
    int cw = wid - 4;
    u32x4 Wf[32];
    f32x16 acc0, acc1;
#pragma unroll
    for (int i = 0; i < 16; ++i) { acc0[i] = 0.f; acc1[i] = 0.f; }

    auto prefW_half = [&](int j, int sb) {
#pragma unroll
        for (int t = 0; t < 2; ++t) {
            int otg = cw*2 + t;
            const u32x4* wb = (const u32x4*)wr + ((size_t)((j*8 + otg)*16))*64 + lane;
#pragma unroll
            for (int s = 0; s < 8; ++s) Wf[t*16 + sb*8 + s] = wb[(sb*8 + s)*64];
        }
    };

    auto gemm_half = [&](int j, int sb) {
        const char* plb = (j & 1) ? Pl[1] : Pl[0];
#pragma unroll
        for (int s = 0; s < 8; ++s) {
            int sk = sb*8 + s;
            int byo = r31*512 + ((sk*32 + l5*16) ^ (r31 << 4));
            f16x8 pf = *(const f16x8*)(plb + byo);
            acc0 = __builtin_amdgcn_mfma_f32_32x32x16_f16(
                __builtin_bit_cast(f16x8, Wf[sk]), pf, acc0, 0, 0, 0);
            acc1 = __builtin_amdgcn_mfma_f32_32x32x16_f16(
                __builtin_bit_cast(f16x8, Wf[16 + sk]), pf, acc1, 0, 0, 0);
        }
    };

    // ---- prologue ----
    __syncthreads();                       // bx_lds + pads visible
    tablesW(0); tablesW(1); tablesW(2); tablesW(3);
    __syncthreads();                       // tabs/pbs visible
    if (producer) {
        stage(0); stage(1); stage(2);
        asm volatile("s_waitcnt vmcnt(14)" ::: "memory");
        __builtin_amdgcn_sched_barrier(0);
        pool(0);
        asm volatile("s_waitcnt lgkmcnt(0)" ::: "memory");
    } else {
        prefW_half(0, 0); prefW_half(0, 1);
    }
    __builtin_amdgcn_s_barrier();
    __builtin_amdgcn_sched_barrier(0);

    // ---- main loop ----
#pragma unroll
    for (int j = 0; j < 8; ++j) {
        if (producer) {
            if (j < 5) stage(j+3);
            if (j < 7) {
                if (j < 5)       asm volatile("s_waitcnt vmcnt(14)" ::: "memory");
                else if (j == 5) asm volatile("s_waitcnt vmcnt(7)"  ::: "memory");
                else             asm volatile("s_waitcnt vmcnt(0)"  ::: "memory");
                __builtin_amdgcn_sched_barrier(0);
                pool(j+1);
            }
            if (j < 4) tablesW(j+4);
            asm volatile("s_waitcnt lgkmcnt(0)" ::: "memory");
        } else {
            gemm_half(j, 0);
            if (j < 7) prefW_half(j+1, 0);
            gemm_half(j, 1);
            if (j < 7) prefW_half(j+1, 1);
            asm volatile("s_waitcnt lgkmcnt(0)" ::: "memory");
        }
        __builtin_amdgcn_s_barrier();
        __builtin_amdgcn_sched_barrier(0);
    }

    // ---- epilogue: consumers write out (bias + relu) ----
    if (!producer) {
        int hw = hw0 + r31;
        bool ok = r31 < HWn;
        float* ob = out + (size_t)n*12544 + hw;
#pragma unroll
        for (int t = 0; t < 2; ++t) {
            f32x16 a = t ? acc1 : acc0;
            int otb = (cw*2 + t)*32;
#pragma unroll
            for (int reg = 0; reg < 16; ++reg) {
                int o = otb + (reg & 3) + 8*(reg >> 2) + 4*l5;
                float v = a[reg] + bfuse[o];
                if (ok) ob[(size_t)o*49] = fmaxf(v, 0.f);
            }
        }
    }
}

extern "C" void kernel_launch(void* const* d_in, const int* in_sizes, int n_in,
                              void* d_out, int out_size, void* d_ws, size_t ws_size,
                              hipStream_t stream) {
    const float* feat  = (const float*)d_in[0];
    const float* boxes = (const float*)d_in[1];
    const float* wf    = (const float*)d_in[2];
    const float* bfuse = (const float*)d_in[3];
    float* out = (float*)d_out;

    char* ws = (char*)d_ws;
    __half* wr    = (__half*)ws;                  // 1 MB (permuted W, fp16)
    __half* featT = (__half*)(ws + (1u<<20));     // 2 MB (fp16 feat, pix-major)

    k_prep<<<512, 256, 0, stream>>>(feat, featT, wf, wr);
    k_fused<<<256, 512, 0, stream>>>(featT, boxes, wr, bfuse, out);
}

// Round 17
// 29.270 us; speedup vs baseline: 1.2515x; 1.0118x over previous
//
#include <hip/hip_runtime.h>
#include <hip/hip_fp16.h>

#define SCALE (1.0f/16.0f)

typedef __attribute__((ext_vector_type(8))) _Float16 f16x8;
typedef __attribute__((ext_vector_type(4))) float f32x4;
typedef __attribute__((ext_vector_type(16))) float f32x16;
typedef __attribute__((ext_vector_type(4))) unsigned int u32x4;
typedef unsigned int u32;

__device__ __forceinline__ void gload16(const void* g, void* l) {
    __builtin_amdgcn_global_load_lds(
        (const __attribute__((address_space(1))) unsigned int*)g,
        (__attribute__((address_space(3))) unsigned int*)l, 16, 0, 0);
}
__device__ __forceinline__ __half2 asH2(u32 v) {
    union { u32 i; __half2 h; } u; u.i = v; return u.h;
}
__device__ __forceinline__ u32 asU32(__half2 h) {
    union { __half2 h; u32 i; } u; u.h = h; return u.i;
}
__device__ __forceinline__ int dupH2(float f) {
    __half h = __float2half_rn(f);
    __half2 d; d.x = h; d.y = h;
    union { __half2 h2; int i; } u; u.h2 = d; return u.i;
}

// ---------------- K1: prep = transpose (blocks 0..255) + permw (blocks 256..511) ----------------
__global__ void k_prep(const float* __restrict__ feat, __half* __restrict__ featT,
                       const float* __restrict__ wf, __half* __restrict__ wr) {
    __shared__ float t[64][65];
    int b = blockIdx.x;
    if (b < 256) {
        int cb = (b >> 6) << 6;
        int pb = (b & 63) << 6;
        int lx = threadIdx.x & 63, ly = threadIdx.x >> 6;
#pragma unroll
        for (int i = 0; i < 16; ++i) {
            int cl = i*4 + ly;
            t[cl][lx] = feat[(size_t)(cb + cl) * 4096 + pb + lx];
        }
        __syncthreads();
#pragma unroll
        for (int i = 0; i < 16; ++i) {
            int pl = i*4 + ly;
            featT[(size_t)(pb + pl) * 256 + cb + lx] = __float2half_rn(t[lx][pl]);
        }
    } else {
        int ch = (b - 256) * 256 + threadIdx.x;
        int l  = ch & 63;
        int sk = (ch >> 6) & 15;
        int ot = (ch >> 10) & 7;
        int j  = ch >> 13;
        int o = ot*32 + (l & 31);
        int k = j*256 + sk*16 + (l >> 5)*8;
        const float* src = wf + (size_t)o*2048 + k;
        f32x4 a = *(const f32x4*)src;
        f32x4 bb = *(const f32x4*)(src + 4);
        f16x8 p;
#pragma unroll
        for (int u = 0; u < 4; ++u) p[u] = (_Float16)a[u];
#pragma unroll
        for (int u = 0; u < 4; ++u) p[4+u] = (_Float16)bb[u];
        *((f16x8*)wr + ch) = p;
    }
}

// ---------------- K2: fused ROIAlign + GEMM, prod/cons + raw barriers + counted vmcnt ----------------
// Grid 256: (n 0..127, hh 0..1), hw split 25/24. 512 thr = 8 waves; waves 0-3 produce,
// waves 4-7 consume. Pool fully unrolled (predicated) so all LDS latency chains overlap.
__global__ void __launch_bounds__(512) k_fused(
    const __half* __restrict__ featT,
    const float* __restrict__ boxes,
    const __half* __restrict__ wr,
    const float* __restrict__ bfuse,
    float* __restrict__ out)
{
    __shared__ char patch[3][28672];
    __shared__ char Pl[2][16384];
    __shared__ int4 tabs[4][2][7];
    __shared__ int  pbs[4][2];
    __shared__ float bx_lds[32];

    int tid = threadIdx.x;
    int lane = tid & 63, wid = tid >> 6;
    int r31 = lane & 31, l5 = lane >> 5;
    int bid = blockIdx.x;
    int n  = bid & 127;
    int hh = bid >> 7;
    int hw0 = hh * 25;
    int HWn = hh ? 24 : 25;
    bool producer = wid < 4;

    int nb_base = (n & 15) * 8;
    int off = n >> 4;
    int t3 = off + (off >= 4 ? 1 : 0);
    int ci = t3 / 3, cj = t3 - ci*3;

    if (tid < 32) bx_lds[tid] = boxes[nb_base*4 + tid];
    {
        int padrows = 32 - HWn;                       // 7 or 8
        for (int i = tid; i < padrows*32*2; i += 512) {
            int b = i / (padrows*32);
            int rem = i - b*(padrows*32);
            int row = HWn + (rem >> 5), slot = rem & 31;
            *(u32x4*)(Pl[b] + row*512 + slot*16) = (u32x4){0,0,0,0};
        }
    }

    auto tablesW = [&](int jj) {
        if (wid < 2) {
            int isy = wid;
            float bx1 = bx_lds[jj*4+0], by1 = bx_lds[jj*4+1];
            float bx2 = bx_lds[jj*4+2], by2 = bx_lds[jj*4+3];
            float w3 = (bx2-bx1)*(1.f/3.f), h3 = (by2-by1)*(1.f/3.f);
            float org  = isy ? (by1 + ci*h3)*SCALE - 0.5f : (bx1 + cj*w3)*SCALE - 0.5f;
            float step = (isy ? h3 : w3) * (SCALE*(1.f/14.f));
            float sc = isy ? 0.25f : 1.f;
            float p = org + ((float)lane + 0.5f)*step;
            float pc = fminf(fmaxf(p, 0.f), 63.f);
            float fl = fminf(floorf(pc), 62.f);
            float fr = pc - fl;
            float c0 = __shfl(fl, 2*lane);
            float c1 = __shfl(fl, 2*lane+1);
            float f  = __shfl(fr, 2*lane);
            float f2 = __shfl(fr, 2*lane+1);
            float fl0 = __shfl(fl, 0);
            int base = min((int)fl0, 56);
            float d = c1 - c0;
            float a0 = sc*((1.f-f) + (1.f-d)*(1.f-f2));
            float a1 = sc*(f + (1.f-d)*f2 + d*(1.f-f2));
            float a2 = sc*(d*f2);
            if (lane < 7) {
                int4 e;
                e.x = (int)c0 - base;
                e.y = dupH2(a0); e.z = dupH2(a1); e.w = dupH2(a2);
                tabs[jj & 3][isy][lane] = e;
            }
            if (lane == 0) pbs[jj & 3][isy] = base;
        }
    };

    auto stage = [&](int jj) {           // exactly 7 gload16 per producer wave
        int xb = pbs[jj & 3][0], yb = pbs[jj & 3][1];
        char* pd = patch[jj % 3];
#pragma unroll
        for (int i = 0; i < 7; ++i) {
            int seg = wid + 4*i;
            int row = seg >> 2, q = seg & 3;
            const __half* src = featT + ((size_t)((yb + row)*64 + xb))*256 + q*512 + lane*8;
            gload16(src, pd + row*4096 + q*1024);
        }
    };

    // pool: compile-time 4-iteration predicated unroll — all LDS chains overlap
    auto pool = [&](int jj) {
        int buf = jj & 1;
        int co = tid & 31;
        int e0 = tid >> 5;
        const char* pb = patch[jj % 3] + co*16;
#pragma unroll
        for (int it = 0; it < 4; ++it) {
            if (it*8 < HWn) {                        // wave-uniform guard
                int e = e0 + it*8;
                bool on = e < HWn;
                int ec = on ? e : 0;
                int g = hw0 + ec;
                int h = (g*37) >> 8, w = g - h*7;
                int4 tx = tabs[jj & 3][0][w], ty = tabs[jj & 3][1][h];
                int px0 = tx.x, py0 = ty.x;
                int lx2 = min(px0 + 2, 7), ly2 = min(py0 + 2, 6);
                const char* r0 = pb + (py0*8 + px0)*512;
                const char* r1 = pb + (min(py0+1,6)*8 + px0)*512;
                const char* r2 = pb + (ly2*8 + px0)*512;
                int dx2 = (lx2 - px0)*512;
                u32x4 F00 = *(const u32x4*)(r0);
                u32x4 F01 = *(const u32x4*)(r0 + 512);
                u32x4 F02 = *(const u32x4*)(r0 + dx2);
                u32x4 F10 = *(const u32x4*)(r1);
                u32x4 F11 = *(const u32x4*)(r1 + 512);
                u32x4 F12 = *(const u32x4*)(r1 + dx2);
                u32x4 F20 = *(const u32x4*)(r2);
                u32x4 F21 = *(const u32x4*)(r2 + 512);
                u32x4 F22 = *(const u32x4*)(r2 + dx2);
                __half2 xa = asH2(tx.y), xb2 = asH2(tx.z), xc = asH2(tx.w);
                __half2 ya = asH2(ty.y), yb2 = asH2(ty.z), yc = asH2(ty.w);
                u32x4 res;
#pragma unroll
                for (int s = 0; s < 4; ++s) {
                    __half2 q0 = __hfma2(asH2(F02[s]), xc, __hfma2(asH2(F01[s]), xb2, __hmul2(asH2(F00[s]), xa)));
                    __half2 q1 = __hfma2(asH2(F12[s]), xc, __hfma2(asH2(F11[s]), xb2, __hmul2(asH2(F10[s]), xa)));
                    __half2 q2 = __hfma2(asH2(F22[s]), xc, __hfma2(asH2(F21[s]), xb2, __hmul2(asH2(F20[s]), xa)));
                    res[s] = asU32(__hfma2(q2, yc, __hfma2(q1, yb2, __hmul2(q0, ya))));
                }
                if (on)
                    *(u32x4*)(Pl[buf] + ec*512 + ((co*16) ^ ((ec & 31) << 4))) = res;
            }
        }
    };

    // consumer: 2 o-tiles x 16 sk, half-interleaved reload
    int cw = wid - 4;
    u32x4 Wf[32];
    f32x16 acc0, acc1;
#pragma unroll
    for (int i = 0; i < 16; ++i) { acc0[i] = 0.f; acc1[i] = 0.f; }

    auto prefW_half = [&](int j, int sb) {
#pragma unroll
        for (int t = 0; t < 2; ++t) {
            int otg = cw*2 + t;
            const u32x4* wb = (const u32x4*)wr + ((size_t)((j*8 + otg)*16))*64 + lane;
#pragma unroll
            for (int s = 0; s < 8; ++s) Wf[t*16 + sb*8 + s] = wb[(sb*8 + s)*64];
        }
    };

    auto gemm_half = [&](int j, int sb) {
        const char* plb = (j & 1) ? Pl[1] : Pl[0];
#pragma unroll
        for (int s = 0; s < 8; ++s) {
            int sk = sb*8 + s;
            int byo = r31*512 + ((sk*32 + l5*16) ^ (r31 << 4));
            f16x8 pf = *(const f16x8*)(plb + byo);
            acc0 = __builtin_amdgcn_mfma_f32_32x32x16_f16(
                __builtin_bit_cast(f16x8, Wf[sk]), pf, acc0, 0, 0, 0);
            acc1 = __builtin_amdgcn_mfma_f32_32x32x16_f16(
                __builtin_bit_cast(f16x8, Wf[16 + sk]), pf, acc1, 0, 0, 0);
        }
    };

    // ---- prologue ----
    __syncthreads();                       // bx_lds + pads visible
    tablesW(0); tablesW(1); tablesW(2); tablesW(3);
    __syncthreads();                       // tabs/pbs visible
    if (producer) {
        stage(0); stage(1); stage(2);
        asm volatile("s_waitcnt vmcnt(14)" ::: "memory");
        __builtin_amdgcn_sched_barrier(0);
        pool(0);
        asm volatile("s_waitcnt lgkmcnt(0)" ::: "memory");
    } else {
        prefW_half(0, 0); prefW_half(0, 1);
    }
    __builtin_amdgcn_s_barrier();
    __builtin_amdgcn_sched_barrier(0);

    // ---- main loop ----
#pragma unroll
    for (int j = 0; j < 8; ++j) {
        if (producer) {
            if (j < 5) stage(j+3);
            if (j < 7) {
                if (j < 5)       asm volatile("s_waitcnt vmcnt(14)" ::: "memory");
                else if (j == 5) asm volatile("s_waitcnt vmcnt(7)"  ::: "memory");
                else             asm volatile("s_waitcnt vmcnt(0)"  ::: "memory");
                __builtin_amdgcn_sched_barrier(0);
                pool(j+1);
            }
            if (j < 4) tablesW(j+4);
            asm volatile("s_waitcnt lgkmcnt(0)" ::: "memory");
        } else {
            gemm_half(j, 0);
            if (j < 7) prefW_half(j+1, 0);
            gemm_half(j, 1);
            if (j < 7) prefW_half(j+1, 1);
            asm volatile("s_waitcnt lgkmcnt(0)" ::: "memory");
        }
        __builtin_amdgcn_s_barrier();
        __builtin_amdgcn_sched_barrier(0);
    }

    // ---- epilogue: consumers write out (bias + relu) ----
    if (!producer) {
        int hw = hw0 + r31;
        bool ok = r31 < HWn;
        float* ob = out + (size_t)n*12544 + hw;
#pragma unroll
        for (int t = 0; t < 2; ++t) {
            f32x16 a = t ? acc1 : acc0;
            int otb = (cw*2 + t)*32;
#pragma unroll
            for (int reg = 0; reg < 16; ++reg) {
                int o = otb + (reg & 3) + 8*(reg >> 2) + 4*l5;
                float v = a[reg] + bfuse[o];
                if (ok) ob[(size_t)o*49] = fmaxf(v, 0.f);
            }
        }
    }
}

extern "C" void kernel_launch(void* const* d_in, const int* in_sizes, int n_in,
                              void* d_out, int out_size, void* d_ws, size_t ws_size,
                              hipStream_t stream) {
    const float* feat  = (const float*)d_in[0];
    const float* boxes = (const float*)d_in[1];
    const float* wf    = (const float*)d_in[2];
    const float* bfuse = (const float*)d_in[3];
    float* out = (float*)d_out;

    char* ws = (char*)d_ws;
    __half* wr    = (__half*)ws;                  // 1 MB (permuted W, fp16)
    __half* featT = (__half*)(ws + (1u<<20));     // 2 MB (fp16 feat, pix-major)

    k_prep<<<512, 256, 0, stream>>>(feat, featT, wf, wr);
    k_fused<<<256, 512, 0, stream>>>(featT, boxes, wr, bfuse, out);
}